// Round 8
// baseline (401.632 us; speedup 1.0000x reference)
//
#include <hip/hip_runtime.h>
#include <hip/hip_bf16.h>
#include <cstdint>
#include <cstddef>

#define D 128
#define SBLK 512
#define SBBITS 10                 // 1024 nodes per super-bucket
#define NSB 128                   // bucket slots (100000>>10 = 97 used)
#define TILE 4096                 // edges per k_bin block
#define BINT 512                  // threads in k_bin

typedef __attribute__((ext_vector_type(8))) short short8;
typedef __attribute__((ext_vector_type(4))) float f32x4;

__device__ __forceinline__ unsigned short f2bf(float f) {
    union { float f; unsigned u; } v; v.f = f;
    unsigned r = v.u + 0x7FFF + ((v.u >> 16) & 1);   // RNE
    return (unsigned short)(r >> 16);
}
__device__ __forceinline__ float bflo(unsigned p) {
    union { unsigned u; float f; } v; v.u = p << 16; return v.f;
}
__device__ __forceinline__ float bfhi(unsigned p) {
    union { unsigned u; float f; } v; v.u = p & 0xFFFF0000u; return v.f;
}

// ---- prep: detect int64 (b0), W->bf16 (all), zero g_sbcnt (b63) ----
__global__ __launch_bounds__(256) void k_prep(const unsigned* __restrict__ ei, int E,
                                              int* __restrict__ flag,
                                              const float* __restrict__ W,
                                              unsigned short* __restrict__ Wbf,
                                              int* __restrict__ g_sbcnt) {
    int t = threadIdx.x, b = blockIdx.x;
    int i = b * 256 + t;
    if (i < D * D) Wbf[i] = f2bf(W[i]);
    if (b == 0 && t == 0) {
        int n = E < 256 ? E : 256;
        int allz = 1;
        for (int k = 0; k < n; ++k) {
            if (ei[2 * k + 1] != 0u) { allz = 0; break; }
        }
        *flag = allz;
    }
    if (b == 63 && t < NSB) g_sbcnt[t] = 0;
}

// ---- GEMM: h = x @ W^T (bf16 MFMA); x staged through LDS (coalesced) ----
__global__ __launch_bounds__(256) void k_gemm(const float* __restrict__ x,
                                              const unsigned short* __restrict__ Wbf,
                                              unsigned short* __restrict__ h, int M) {
    __shared__ unsigned short sx[64 * 136];      // 64 rows, pad 128->136 (bank spread)
    int t = threadIdx.x;
    int base = blockIdx.x * 64;

#pragma unroll
    for (int j = 0; j < 8; ++j) {
        int idx = j * 256 + t;                   // 2048 float4 chunks
        int row = idx >> 5, c4 = (idx & 31) * 4;
        int gr = base + row;
        float4 v = (gr < M) ? *(const float4*)(x + (size_t)gr * D + c4)
                            : make_float4(0.f, 0.f, 0.f, 0.f);
        unsigned short* dst = &sx[row * 136 + c4];
        dst[0] = f2bf(v.x); dst[1] = f2bf(v.y); dst[2] = f2bf(v.z); dst[3] = f2bf(v.w);
    }
    __syncthreads();

    int wave = t >> 6, lane = t & 63;
    int lr = lane & 15, lg = lane >> 4;
    int lrow = wave * 16 + lr;
    f32x4 acc[8];
#pragma unroll
    for (int i = 0; i < 8; ++i) acc[i] = (f32x4){0.f, 0.f, 0.f, 0.f};

#pragma unroll
    for (int ks = 0; ks < 4; ++ks) {
        int k0 = ks * 32 + lg * 8;
        short8 af = *(const short8*)(&sx[lrow * 136 + k0]);
#pragma unroll
        for (int nt = 0; nt < 8; ++nt) {
            short8 bf = *(const short8*)(Wbf + (size_t)(nt * 16 + lr) * D + k0);
            acc[nt] = __builtin_amdgcn_mfma_f32_16x16x32_bf16(af, bf, acc[nt], 0, 0, 0);
        }
    }
    int m0 = base + wave * 16;
#pragma unroll
    for (int nt = 0; nt < 8; ++nt) {
#pragma unroll
        for (int r = 0; r < 4; ++r) {
            int rr = m0 + lg * 4 + r;
            if (rr < M) h[(size_t)rr * D + nt * 16 + lr] = f2bf(acc[nt][r]);
        }
    }
}

// ---- pass 1: tile-local LDS sort into 128 super-buckets, contiguous flush ----
// entry = src | (dstLocal << 17); src < 2^17, dstLocal < 1024
__global__ __launch_bounds__(BINT) void k_bin(const int* __restrict__ ei, int E,
                                              const int* __restrict__ flagp,
                                              int* __restrict__ g_sbcnt,
                                              unsigned* __restrict__ binned, int C2) {
    __shared__ unsigned stage[TILE];
    __shared__ unsigned char ssb[TILE];
    __shared__ int hcnt[NSB], hoff[NSB], lcur[NSB], gbase[NSB];
    int f64 = *flagp;
    int t = threadIdx.x;
    int base = blockIdx.x * TILE;
    int cnt = E - base; if (cnt > TILE) cnt = TILE;

    if (t < NSB) hcnt[t] = 0;
    __syncthreads();

    unsigned ent[8]; int esb[8];
#pragma unroll
    for (int j = 0; j < 8; ++j) {
        int idx = j * BINT + t;
        esb[j] = -1;
        if (idx < cnt) {
            int e = base + idx;
            int s, d;
            if (f64) {
                s = ((const int2*)ei)[e].x;
                d = ((const int2*)ei)[E + e].x;
            } else {
                s = ei[e];
                d = ei[E + e];
            }
            esb[j] = d >> SBBITS;
            ent[j] = (unsigned)s | ((unsigned)(d & ((1 << SBBITS) - 1)) << 17);
            atomicAdd(&hcnt[esb[j]], 1);
        }
    }
    __syncthreads();
    if (t < NSB) hoff[t] = hcnt[t];
    __syncthreads();
#pragma unroll
    for (int off = 1; off < NSB; off <<= 1) {
        int a = (t < NSB && t >= off) ? hoff[t - off] : 0;
        __syncthreads();
        if (t < NSB) hoff[t] += a;
        __syncthreads();
    }
    if (t < NSB) {
        int ex = hoff[t] - hcnt[t];            // exclusive offset
        lcur[t] = ex;
        hoff[t] = ex;
        gbase[t] = (hcnt[t] > 0) ? atomicAdd(&g_sbcnt[t], hcnt[t]) : 0;
    }
    __syncthreads();
#pragma unroll
    for (int j = 0; j < 8; ++j) {
        if (esb[j] >= 0) {
            int p = atomicAdd(&lcur[esb[j]], 1);
            stage[p] = ent[j];
            ssb[p] = (unsigned char)esb[j];
        }
    }
    __syncthreads();
    for (int i = t; i < cnt; i += BINT) {      // lanes write consecutive addrs
        int sb = ssb[i];
        int pos = gbase[sb] + (i - hoff[sb]);
        if (pos < C2) binned[(size_t)sb * C2 + pos] = stage[i];
    }
}

// ---- pass 2: per-super-bucket degree/scan/fill within L2-resident window ----
__global__ __launch_bounds__(1024) void k_fill2(const unsigned* __restrict__ binned, int C2,
                                                const int* __restrict__ g_sbcnt,
                                                int2* __restrict__ ronode,
                                                float* __restrict__ dinv,
                                                int* __restrict__ csrc, int N) {
    __shared__ int deg[1024];
    __shared__ int scn[1024];
    __shared__ int cur[1024];
    int b = blockIdx.x, t = threadIdx.x;
    int cnt = g_sbcnt[b]; if (cnt > C2) cnt = C2;
    const unsigned* ent = binned + (size_t)b * C2;

    deg[t] = 0;
    __syncthreads();
    for (int i = t; i < cnt; i += 1024) atomicAdd(&deg[ent[i] >> 17], 1);
    __syncthreads();
    scn[t] = deg[t];
    __syncthreads();
    for (int off = 1; off < 1024; off <<= 1) {
        int a = (t >= off) ? scn[t - off] : 0;
        __syncthreads();
        scn[t] += a;
        __syncthreads();
    }
    int ex = scn[t] - deg[t];
    cur[t] = ex;
    int node = (b << SBBITS) + t;
    if (node < N) {
        ronode[node] = make_int2(b * C2 + ex, deg[t]);
        dinv[node] = deg[t] > 0 ? rsqrtf((float)deg[t]) : 0.0f;
    }
    __syncthreads();
    for (int i = t; i < cnt; i += 1024) {
        unsigned e = ent[i];
        int pos = atomicAdd(&cur[e >> 17], 1);
        csrc[b * C2 + pos] = (int)(e & 0x1FFFF);
    }
}

// ---- aggregation: 1 wave/node, dwordx2 loads, 32-edge main loop (16 in flight) ----
__global__ __launch_bounds__(256) void k_agg(const unsigned long long* __restrict__ h,
                                             const int* __restrict__ csrc,
                                             const int2* __restrict__ ronode,
                                             const float* __restrict__ dinv,
                                             float4* __restrict__ out, int N) {
    int wave = threadIdx.x >> 6, lane = threadIdx.x & 63;
    int node = blockIdx.x * 4 + wave;
    if (node >= N) return;
    int half = lane >> 5, lq = lane & 31;   // lq: 4-col group; half: edge parity
    int2 ro = ronode[node];
    int beg = ro.x, end = ro.x + ro.y;
    float a0 = 0.f, a1 = 0.f, a2 = 0.f, a3 = 0.f;
    int i = beg;
    for (; i + 32 <= end; i += 32) {
#pragma unroll
        for (int p = 0; p < 16; ++p) {
            int e = i + 2 * p + half;
            int s = csrc[e];
            float w = dinv[s];
            unsigned long long pk = h[(size_t)s * 32 + lq];
            unsigned lo = (unsigned)pk, hi = (unsigned)(pk >> 32);
            a0 += w * bflo(lo); a1 += w * bfhi(lo);
            a2 += w * bflo(hi); a3 += w * bfhi(hi);
        }
    }
    if (i + 16 <= end) {
#pragma unroll
        for (int p = 0; p < 8; ++p) {
            int e = i + 2 * p + half;
            int s = csrc[e];
            float w = dinv[s];
            unsigned long long pk = h[(size_t)s * 32 + lq];
            unsigned lo = (unsigned)pk, hi = (unsigned)(pk >> 32);
            a0 += w * bflo(lo); a1 += w * bfhi(lo);
            a2 += w * bflo(hi); a3 += w * bfhi(hi);
        }
        i += 16;
    }
    for (; i + 2 <= end; i += 2) {
        int e = i + half;
        int s = csrc[e];
        float w = dinv[s];
        unsigned long long pk = h[(size_t)s * 32 + lq];
        unsigned lo = (unsigned)pk, hi = (unsigned)(pk >> 32);
        a0 += w * bflo(lo); a1 += w * bfhi(lo);
        a2 += w * bflo(hi); a3 += w * bfhi(hi);
    }
    if (i < end) {                           // odd leftover: upper half weight 0
        int s = csrc[i];
        float w = half ? 0.f : dinv[s];
        unsigned long long pk = h[(size_t)s * 32 + lq];
        unsigned lo = (unsigned)pk, hi = (unsigned)(pk >> 32);
        a0 += w * bflo(lo); a1 += w * bfhi(lo);
        a2 += w * bflo(hi); a3 += w * bfhi(hi);
    }
    a0 += __shfl_xor(a0, 32);
    a1 += __shfl_xor(a1, 32);
    a2 += __shfl_xor(a2, 32);
    a3 += __shfl_xor(a3, 32);
    float sd = dinv[node];
    if (half == 0)
        out[(size_t)node * 32 + lq] = make_float4(a0 * sd, a1 * sd, a2 * sd, a3 * sd);
}

// ---- BN stats: block partials (sum, sumsq) per column ----
__global__ __launch_bounds__(256) void k_stats(const float* __restrict__ agg,
                                               float* __restrict__ part, int N) {
    int t = threadIdx.x;
    int c = t & 127, half = t >> 7;
    float s = 0.f, q = 0.f;
    for (int r = blockIdx.x * 2 + half; r < N; r += SBLK * 2) {
        float v = agg[(size_t)r * 128 + c];
        s += v; q += v * v;
    }
    __shared__ float sh[512];
    sh[t] = s; sh[256 + t] = q;
    __syncthreads();
    if (t < 128) {
        part[blockIdx.x * 256 + t]       = sh[t] + sh[t + 128];
        part[blockIdx.x * 256 + 128 + t] = sh[256 + t] + sh[256 + t + 128];
    }
}

__global__ void k_params(const float* __restrict__ part, const float* __restrict__ gamma,
                         const float* __restrict__ beta, float* __restrict__ params, int N) {
    int t = threadIdx.x;   // 256
    float a = 0.f;
    for (int b = 0; b < SBLK; ++b) a += part[b * 256 + t];
    __shared__ float sh[256];
    sh[t] = a;
    __syncthreads();
    if (t < 128) {
        float mean = sh[t] / (float)N;
        float var = sh[128 + t] / (float)N - mean * mean;
        var = var > 0.f ? var : 0.f;
        float sc = gamma[t] * rsqrtf(var + 1e-5f);
        params[t] = sc;
        params[128 + t] = beta[t] - mean * sc;
    }
}

// ---- finalize in-place: out = relu(agg*scale+shift) + x ----
__global__ __launch_bounds__(256) void k_final(float4* __restrict__ out,
                                               const float4* __restrict__ x,
                                               const float* __restrict__ params, int n4) {
    const float4* p4 = (const float4*)params;
    for (int i = blockIdx.x * 256 + threadIdx.x; i < n4; i += gridDim.x * 256) {
        int c = i & 31;
        float4 s = p4[c], b = p4[32 + c];
        float4 v = out[i], xv = x[i];
        float4 r;
        r.x = fmaxf(v.x * s.x + b.x, 0.f) + xv.x;
        r.y = fmaxf(v.y * s.y + b.y, 0.f) + xv.y;
        r.z = fmaxf(v.z * s.z + b.z, 0.f) + xv.z;
        r.w = fmaxf(v.w * s.w + b.w, 0.f) + xv.w;
        out[i] = r;
    }
}

extern "C" void kernel_launch(void* const* d_in, const int* in_sizes, int n_in,
                              void* d_out, int out_size, void* d_ws, size_t ws_size,
                              hipStream_t stream) {
    const float* x     = (const float*)d_in[0];
    const int*   ei    = (const int*)d_in[1];
    const float* W     = (const float*)d_in[2];
    const float* gamma = (const float*)d_in[3];
    const float* beta  = (const float*)d_in[4];

    int N = in_sizes[0] / D;
    int E = in_sizes[1] / 2;
    int NSBu = (N + (1 << SBBITS) - 1) >> SBBITS;          // used super-buckets (<=NSB)
    int avg = (E + NSBu - 1) / NSBu;
    int C2 = ((avg + 4096 + 63) / 64) * 64;                // ~+22 sigma headroom

    char* ws = (char*)d_ws;
    size_t off = 0;
    auto alloc = [&](size_t bytes) { size_t o = off; off = (off + bytes + 255) & ~(size_t)255; return o; };

    unsigned short* h    = (unsigned short*)(ws + alloc((size_t)N * D * 2));
    int*      csrc   = (int*)     (ws + alloc((size_t)NSBu * C2 * 4));
    unsigned* binned = (unsigned*)(ws + alloc((size_t)NSBu * C2 * 4));
    int*      g_sbcnt= (int*)     (ws + alloc((size_t)NSB * 4));
    float*    dinv   = (float*)   (ws + alloc((size_t)N * 4));
    int2*     ronode = (int2*)    (ws + alloc((size_t)N * 8));
    float*    part   = (float*)   (ws + alloc((size_t)SBLK * 256 * 4));
    float*    params = (float*)   (ws + alloc(256 * 4));
    int*      flagp  = (int*)     (ws + alloc(4));
    unsigned short* Wbf = (unsigned short*)(ws + alloc((size_t)D * D * 2));

    float* outf = (float*)d_out;

    k_prep<<<64, 256, 0, stream>>>((const unsigned*)ei, E, flagp, W, Wbf, g_sbcnt);
    k_gemm<<<(N + 63) / 64, 256, 0, stream>>>(x, Wbf, h, N);
    k_bin<<<(E + TILE - 1) / TILE, BINT, 0, stream>>>(ei, E, flagp, g_sbcnt, binned, C2);
    k_fill2<<<NSBu, 1024, 0, stream>>>(binned, C2, g_sbcnt, ronode, dinv, csrc, N);
    k_agg<<<(N + 3) / 4, 256, 0, stream>>>((const unsigned long long*)h, csrc, ronode, dinv,
                                           (float4*)d_out, N);
    k_stats<<<SBLK, 256, 0, stream>>>(outf, part, N);
    k_params<<<1, 256, 0, stream>>>(part, gamma, beta, params, N);
    k_final<<<2048, 256, 0, stream>>>((float4*)d_out, (const float4*)x, params,
                                      (N * D) / 4);
}

// Round 9
// 376.538 us; speedup vs baseline: 1.0666x; 1.0666x over previous
//
#include <hip/hip_runtime.h>
#include <hip/hip_bf16.h>
#include <cstdint>
#include <cstddef>

#define D 128
#define SBLK 512
#define SBBITS 10                 // 1024 nodes per super-bucket
#define NSB 128                   // bucket slots (100000>>10 = 97 used)
#define TILE 4096                 // edges per k_bin block
#define BINT 512                  // threads in k_bin

typedef __attribute__((ext_vector_type(8))) short short8;
typedef __attribute__((ext_vector_type(4))) float f32x4;

__device__ __forceinline__ unsigned short f2bf(float f) {
    union { float f; unsigned u; } v; v.f = f;
    unsigned r = v.u + 0x7FFF + ((v.u >> 16) & 1);   // RNE
    return (unsigned short)(r >> 16);
}
__device__ __forceinline__ float bflo(unsigned p) {
    union { unsigned u; float f; } v; v.u = p << 16; return v.f;
}
__device__ __forceinline__ float bfhi(unsigned p) {
    union { unsigned u; float f; } v; v.u = p & 0xFFFF0000u; return v.f;
}
__device__ __forceinline__ float bf2f(unsigned short u) {
    union { unsigned u; float f; } v; v.u = ((unsigned)u) << 16; return v.f;
}

// ---- prep: detect int64 (b0), W->bf16 (all), zero g_sbcnt (b63) ----
__global__ __launch_bounds__(256) void k_prep(const unsigned* __restrict__ ei, int E,
                                              int* __restrict__ flag,
                                              const float* __restrict__ W,
                                              unsigned short* __restrict__ Wbf,
                                              int* __restrict__ g_sbcnt) {
    int t = threadIdx.x, b = blockIdx.x;
    int i = b * 256 + t;
    if (i < D * D) Wbf[i] = f2bf(W[i]);
    if (b == 0 && t == 0) {
        int n = E < 256 ? E : 256;
        int allz = 1;
        for (int k = 0; k < n; ++k) {
            if (ei[2 * k + 1] != 0u) { allz = 0; break; }
        }
        *flag = allz;
    }
    if (b == 63 && t < NSB) g_sbcnt[t] = 0;
}

// ---- GEMM: h = x @ W^T (bf16 MFMA); x staged through LDS (coalesced) ----
__global__ __launch_bounds__(256) void k_gemm(const float* __restrict__ x,
                                              const unsigned short* __restrict__ Wbf,
                                              unsigned short* __restrict__ h, int M) {
    __shared__ unsigned short sx[64 * 136];      // 64 rows, pad 128->136 (bank spread)
    int t = threadIdx.x;
    int base = blockIdx.x * 64;

#pragma unroll
    for (int j = 0; j < 8; ++j) {
        int idx = j * 256 + t;                   // 2048 float4 chunks
        int row = idx >> 5, c4 = (idx & 31) * 4;
        int gr = base + row;
        float4 v = (gr < M) ? *(const float4*)(x + (size_t)gr * D + c4)
                            : make_float4(0.f, 0.f, 0.f, 0.f);
        unsigned short* dst = &sx[row * 136 + c4];
        dst[0] = f2bf(v.x); dst[1] = f2bf(v.y); dst[2] = f2bf(v.z); dst[3] = f2bf(v.w);
    }
    __syncthreads();

    int wave = t >> 6, lane = t & 63;
    int lr = lane & 15, lg = lane >> 4;
    int lrow = wave * 16 + lr;
    f32x4 acc[8];
#pragma unroll
    for (int i = 0; i < 8; ++i) acc[i] = (f32x4){0.f, 0.f, 0.f, 0.f};

#pragma unroll
    for (int ks = 0; ks < 4; ++ks) {
        int k0 = ks * 32 + lg * 8;
        short8 af = *(const short8*)(&sx[lrow * 136 + k0]);
#pragma unroll
        for (int nt = 0; nt < 8; ++nt) {
            short8 bf = *(const short8*)(Wbf + (size_t)(nt * 16 + lr) * D + k0);
            acc[nt] = __builtin_amdgcn_mfma_f32_16x16x32_bf16(af, bf, acc[nt], 0, 0, 0);
        }
    }
    int m0 = base + wave * 16;
#pragma unroll
    for (int nt = 0; nt < 8; ++nt) {
#pragma unroll
        for (int r = 0; r < 4; ++r) {
            int rr = m0 + lg * 4 + r;
            if (rr < M) h[(size_t)rr * D + nt * 16 + lr] = f2bf(acc[nt][r]);
        }
    }
}

// ---- pass 1: tile-local LDS sort into 128 super-buckets, contiguous flush ----
// entry = src | (dstLocal << 17); src < 2^17, dstLocal < 1024
__global__ __launch_bounds__(BINT) void k_bin(const int* __restrict__ ei, int E,
                                              const int* __restrict__ flagp,
                                              int* __restrict__ g_sbcnt,
                                              unsigned* __restrict__ binned, int C2) {
    __shared__ unsigned stage[TILE];
    __shared__ unsigned char ssb[TILE];
    __shared__ int hcnt[NSB], hoff[NSB], lcur[NSB], gbase[NSB];
    int f64 = *flagp;
    int t = threadIdx.x;
    int base = blockIdx.x * TILE;
    int cnt = E - base; if (cnt > TILE) cnt = TILE;

    if (t < NSB) hcnt[t] = 0;
    __syncthreads();

    unsigned ent[8]; int esb[8];
#pragma unroll
    for (int j = 0; j < 8; ++j) {
        int idx = j * BINT + t;
        esb[j] = -1;
        if (idx < cnt) {
            int e = base + idx;
            int s, d;
            if (f64) {
                s = ((const int2*)ei)[e].x;
                d = ((const int2*)ei)[E + e].x;
            } else {
                s = ei[e];
                d = ei[E + e];
            }
            esb[j] = d >> SBBITS;
            ent[j] = (unsigned)s | ((unsigned)(d & ((1 << SBBITS) - 1)) << 17);
            atomicAdd(&hcnt[esb[j]], 1);
        }
    }
    __syncthreads();
    if (t < NSB) hoff[t] = hcnt[t];
    __syncthreads();
#pragma unroll
    for (int off = 1; off < NSB; off <<= 1) {
        int a = (t < NSB && t >= off) ? hoff[t - off] : 0;
        __syncthreads();
        if (t < NSB) hoff[t] += a;
        __syncthreads();
    }
    if (t < NSB) {
        int ex = hoff[t] - hcnt[t];            // exclusive offset
        lcur[t] = ex;
        hoff[t] = ex;
        gbase[t] = (hcnt[t] > 0) ? atomicAdd(&g_sbcnt[t], hcnt[t]) : 0;
    }
    __syncthreads();
#pragma unroll
    for (int j = 0; j < 8; ++j) {
        if (esb[j] >= 0) {
            int p = atomicAdd(&lcur[esb[j]], 1);
            stage[p] = ent[j];
            ssb[p] = (unsigned char)esb[j];
        }
    }
    __syncthreads();
    for (int i = t; i < cnt; i += BINT) {      // lanes write consecutive addrs
        int sb = ssb[i];
        int pos = gbase[sb] + (i - hoff[sb]);
        if (pos < C2) binned[(size_t)sb * C2 + pos] = stage[i];
    }
}

// ---- pass 2: per-super-bucket degree/scan/fill within L2-resident window ----
__global__ __launch_bounds__(1024) void k_fill2(const unsigned* __restrict__ binned, int C2,
                                                const int* __restrict__ g_sbcnt,
                                                int2* __restrict__ ronode,
                                                float* __restrict__ dinv,
                                                int* __restrict__ csrc, int N) {
    __shared__ int deg[1024];
    __shared__ int scn[1024];
    __shared__ int cur[1024];
    int b = blockIdx.x, t = threadIdx.x;
    int cnt = g_sbcnt[b]; if (cnt > C2) cnt = C2;
    const unsigned* ent = binned + (size_t)b * C2;

    deg[t] = 0;
    __syncthreads();
    for (int i = t; i < cnt; i += 1024) atomicAdd(&deg[ent[i] >> 17], 1);
    __syncthreads();
    scn[t] = deg[t];
    __syncthreads();
    for (int off = 1; off < 1024; off <<= 1) {
        int a = (t >= off) ? scn[t - off] : 0;
        __syncthreads();
        scn[t] += a;
        __syncthreads();
    }
    int ex = scn[t] - deg[t];
    cur[t] = ex;
    int node = (b << SBBITS) + t;
    if (node < N) {
        ronode[node] = make_int2(b * C2 + ex, deg[t]);
        dinv[node] = deg[t] > 0 ? rsqrtf((float)deg[t]) : 0.0f;
    }
    __syncthreads();
    for (int i = t; i < cnt; i += 1024) {
        unsigned e = ent[i];
        int pos = atomicAdd(&cur[e >> 17], 1);
        csrc[b * C2 + pos] = (int)(e & 0x1FFFF);
    }
}

// ---- aggregation: 1 wave/node, dwordx2 loads (2 edges/instr), bf16 agg out ----
__global__ __launch_bounds__(256) void k_agg(const unsigned long long* __restrict__ h,
                                             const int* __restrict__ csrc,
                                             const int2* __restrict__ ronode,
                                             const float* __restrict__ dinv,
                                             ushort4* __restrict__ aggb, int N) {
    int wave = threadIdx.x >> 6, lane = threadIdx.x & 63;
    int node = blockIdx.x * 4 + wave;
    if (node >= N) return;
    int half = lane >> 5, lq = lane & 31;   // lq: 4-col group; half: edge parity
    int2 ro = ronode[node];
    int beg = ro.x, end = ro.x + ro.y;
    float a0 = 0.f, a1 = 0.f, a2 = 0.f, a3 = 0.f;
    int i = beg;
    for (; i + 16 <= end; i += 16) {
#pragma unroll
        for (int p = 0; p < 8; ++p) {
            int e = i + 2 * p + half;
            int s = csrc[e];
            float w = dinv[s];
            unsigned long long pk = h[(size_t)s * 32 + lq];
            unsigned lo = (unsigned)pk, hi = (unsigned)(pk >> 32);
            a0 += w * bflo(lo); a1 += w * bfhi(lo);
            a2 += w * bflo(hi); a3 += w * bfhi(hi);
        }
    }
    for (; i + 2 <= end; i += 2) {
        int e = i + half;
        int s = csrc[e];
        float w = dinv[s];
        unsigned long long pk = h[(size_t)s * 32 + lq];
        unsigned lo = (unsigned)pk, hi = (unsigned)(pk >> 32);
        a0 += w * bflo(lo); a1 += w * bfhi(lo);
        a2 += w * bflo(hi); a3 += w * bfhi(hi);
    }
    if (i < end) {                           // odd leftover: upper half weight 0
        int s = csrc[i];
        float w = half ? 0.f : dinv[s];
        unsigned long long pk = h[(size_t)s * 32 + lq];
        unsigned lo = (unsigned)pk, hi = (unsigned)(pk >> 32);
        a0 += w * bflo(lo); a1 += w * bfhi(lo);
        a2 += w * bflo(hi); a3 += w * bfhi(hi);
    }
    a0 += __shfl_xor(a0, 32);
    a1 += __shfl_xor(a1, 32);
    a2 += __shfl_xor(a2, 32);
    a3 += __shfl_xor(a3, 32);
    float sd = dinv[node];
    if (half == 0) {
        ushort4 o;
        o.x = f2bf(a0 * sd); o.y = f2bf(a1 * sd);
        o.z = f2bf(a2 * sd); o.w = f2bf(a3 * sd);
        aggb[(size_t)node * 32 + lq] = o;
    }
}

// ---- BN stats from bf16 agg: block partials (sum, sumsq) per column ----
__global__ __launch_bounds__(256) void k_stats(const unsigned short* __restrict__ aggb,
                                               float* __restrict__ part, int N) {
    int t = threadIdx.x;
    int c = t & 127, half = t >> 7;
    float s = 0.f, q = 0.f;
    for (int r = blockIdx.x * 2 + half; r < N; r += SBLK * 2) {
        float v = bf2f(aggb[(size_t)r * 128 + c]);
        s += v; q += v * v;
    }
    __shared__ float sh[512];
    sh[t] = s; sh[256 + t] = q;
    __syncthreads();
    if (t < 128) {
        part[blockIdx.x * 256 + t]       = sh[t] + sh[t + 128];
        part[blockIdx.x * 256 + 128 + t] = sh[256 + t] + sh[256 + t + 128];
    }
}

__global__ void k_params(const float* __restrict__ part, const float* __restrict__ gamma,
                         const float* __restrict__ beta, float* __restrict__ params, int N) {
    int t = threadIdx.x;   // 256
    float a = 0.f;
    for (int b = 0; b < SBLK; ++b) a += part[b * 256 + t];
    __shared__ float sh[256];
    sh[t] = a;
    __syncthreads();
    if (t < 128) {
        float mean = sh[t] / (float)N;
        float var = sh[128 + t] / (float)N - mean * mean;
        var = var > 0.f ? var : 0.f;
        float sc = gamma[t] * rsqrtf(var + 1e-5f);
        params[t] = sc;
        params[128 + t] = beta[t] - mean * sc;
    }
}

// ---- finalize: out = relu(aggb*scale+shift) + x  (f32 out, bf16 agg in) ----
__global__ __launch_bounds__(256) void k_final(float4* __restrict__ out,
                                               const ushort4* __restrict__ aggb,
                                               const float4* __restrict__ x,
                                               const float* __restrict__ params, int n4) {
    const float4* p4 = (const float4*)params;
    for (int i = blockIdx.x * 256 + threadIdx.x; i < n4; i += gridDim.x * 256) {
        int c = i & 31;
        float4 s = p4[c], b = p4[32 + c];
        ushort4 av = aggb[i];
        float4 xv = x[i];
        float4 r;
        r.x = fmaxf(bf2f(av.x) * s.x + b.x, 0.f) + xv.x;
        r.y = fmaxf(bf2f(av.y) * s.y + b.y, 0.f) + xv.y;
        r.z = fmaxf(bf2f(av.z) * s.z + b.z, 0.f) + xv.z;
        r.w = fmaxf(bf2f(av.w) * s.w + b.w, 0.f) + xv.w;
        out[i] = r;
    }
}

extern "C" void kernel_launch(void* const* d_in, const int* in_sizes, int n_in,
                              void* d_out, int out_size, void* d_ws, size_t ws_size,
                              hipStream_t stream) {
    const float* x     = (const float*)d_in[0];
    const int*   ei    = (const int*)d_in[1];
    const float* W     = (const float*)d_in[2];
    const float* gamma = (const float*)d_in[3];
    const float* beta  = (const float*)d_in[4];

    int N = in_sizes[0] / D;
    int E = in_sizes[1] / 2;
    int NSBu = (N + (1 << SBBITS) - 1) >> SBBITS;          // used super-buckets (<=NSB)
    int avg = (E + NSBu - 1) / NSBu;
    int C2 = ((avg + 4096 + 63) / 64) * 64;                // ~+22 sigma headroom

    char* ws = (char*)d_ws;
    size_t off = 0;
    auto alloc = [&](size_t bytes) { size_t o = off; off = (off + bytes + 255) & ~(size_t)255; return o; };

    size_t binned_bytes = (size_t)NSBu * C2 * 4;
    size_t aggb_bytes   = (size_t)N * D * 2;
    size_t share_bytes  = binned_bytes > aggb_bytes ? binned_bytes : aggb_bytes;

    unsigned short* h    = (unsigned short*)(ws + alloc((size_t)N * D * 2));
    int*      csrc   = (int*)     (ws + alloc((size_t)NSBu * C2 * 4));
    char*     share  =            (ws + alloc(share_bytes));      // binned, then aggb
    unsigned* binned = (unsigned*)share;
    unsigned short* aggb = (unsigned short*)share;                // alias: binned dead after k_fill2
    int*      g_sbcnt= (int*)     (ws + alloc((size_t)NSB * 4));
    float*    dinv   = (float*)   (ws + alloc((size_t)N * 4));
    int2*     ronode = (int2*)    (ws + alloc((size_t)N * 8));
    float*    part   = (float*)   (ws + alloc((size_t)SBLK * 256 * 4));
    float*    params = (float*)   (ws + alloc(256 * 4));
    int*      flagp  = (int*)     (ws + alloc(4));
    unsigned short* Wbf = (unsigned short*)(ws + alloc((size_t)D * D * 2));

    k_prep<<<64, 256, 0, stream>>>((const unsigned*)ei, E, flagp, W, Wbf, g_sbcnt);
    k_gemm<<<(N + 63) / 64, 256, 0, stream>>>(x, Wbf, h, N);
    k_bin<<<(E + TILE - 1) / TILE, BINT, 0, stream>>>(ei, E, flagp, g_sbcnt, binned, C2);
    k_fill2<<<NSBu, 1024, 0, stream>>>(binned, C2, g_sbcnt, ronode, dinv, csrc, N);
    k_agg<<<(N + 3) / 4, 256, 0, stream>>>((const unsigned long long*)h, csrc, ronode, dinv,
                                           (ushort4*)aggb, N);
    k_stats<<<SBLK, 256, 0, stream>>>(aggb, part, N);
    k_params<<<1, 256, 0, stream>>>(part, gamma, beta, params, N);
    k_final<<<2048, 256, 0, stream>>>((float4*)d_out, (const ushort4*)aggb,
                                      (const float4*)x, params, (N * D) / 4);
}

// Round 11
// 342.076 us; speedup vs baseline: 1.1741x; 1.1007x over previous
//
#include <hip/hip_runtime.h>
#include <hip/hip_bf16.h>
#include <cstdint>
#include <cstddef>

#define D 128
#define SBLK 256                  // k_stats blocks
#define SBBITS 9                  // 512 nodes per super-bucket
#define SBN 512                   // nodes per bucket
#define NSB 256                   // bucket slots (100000>>9 = 196 used)
#define TILE 4096                 // edges per k_bin block
#define BINT 512                  // threads in k_bin

typedef __attribute__((ext_vector_type(8))) short short8;
typedef __attribute__((ext_vector_type(4))) float f32x4;

__device__ __forceinline__ unsigned short f2bf(float f) {
    union { float f; unsigned u; } v; v.f = f;
    unsigned r = v.u + 0x7FFF + ((v.u >> 16) & 1);   // RNE
    return (unsigned short)(r >> 16);
}
__device__ __forceinline__ float bflo(unsigned p) {
    union { unsigned u; float f; } v; v.u = p << 16; return v.f;
}
__device__ __forceinline__ float bfhi(unsigned p) {
    union { unsigned u; float f; } v; v.u = p & 0xFFFF0000u; return v.f;
}
__device__ __forceinline__ float bf2f(unsigned short u) {
    union { unsigned u; float f; } v; v.u = ((unsigned)u) << 16; return v.f;
}

// ---- prep: detect int64 (b0), W->bf16 (all), zero g_sbcnt (b63) ----
__global__ __launch_bounds__(256) void k_prep(const unsigned* __restrict__ ei, int E,
                                              int* __restrict__ flag,
                                              const float* __restrict__ W,
                                              unsigned short* __restrict__ Wbf,
                                              int* __restrict__ g_sbcnt) {
    int t = threadIdx.x, b = blockIdx.x;
    int i = b * 256 + t;
    if (i < D * D) Wbf[i] = f2bf(W[i]);
    if (b == 0 && t == 0) {
        int n = E < 256 ? E : 256;
        int allz = 1;
        for (int k = 0; k < n; ++k) {
            if (ei[2 * k + 1] != 0u) { allz = 0; break; }
        }
        *flag = allz;
    }
    if (b == 63) g_sbcnt[t] = 0;                 // 256 slots
}

// ---- GEMM: h = x @ W^T (bf16 MFMA); x in via LDS, h out via LDS (coalesced) ----
__global__ __launch_bounds__(256) void k_gemm(const float* __restrict__ x,
                                              const unsigned short* __restrict__ Wbf,
                                              unsigned short* __restrict__ h, int M) {
    __shared__ unsigned short sx[64 * 136];      // 64 rows, pad 128->136
    int t = threadIdx.x;
    int base = blockIdx.x * 64;

#pragma unroll
    for (int j = 0; j < 8; ++j) {
        int idx = j * 256 + t;                   // 2048 float4 chunks
        int row = idx >> 5, c4 = (idx & 31) * 4;
        int gr = base + row;
        float4 v = (gr < M) ? *(const float4*)(x + (size_t)gr * D + c4)
                            : make_float4(0.f, 0.f, 0.f, 0.f);
        unsigned short* dst = &sx[row * 136 + c4];
        dst[0] = f2bf(v.x); dst[1] = f2bf(v.y); dst[2] = f2bf(v.z); dst[3] = f2bf(v.w);
    }
    __syncthreads();

    int wave = t >> 6, lane = t & 63;
    int lr = lane & 15, lg = lane >> 4;
    int lrow = wave * 16 + lr;
    f32x4 acc[8];
#pragma unroll
    for (int i = 0; i < 8; ++i) acc[i] = (f32x4){0.f, 0.f, 0.f, 0.f};

#pragma unroll
    for (int ks = 0; ks < 4; ++ks) {
        int k0 = ks * 32 + lg * 8;
        short8 af = *(const short8*)(&sx[lrow * 136 + k0]);
#pragma unroll
        for (int nt = 0; nt < 8; ++nt) {
            short8 bf = *(const short8*)(Wbf + (size_t)(nt * 16 + lr) * D + k0);
            acc[nt] = __builtin_amdgcn_mfma_f32_16x16x32_bf16(af, bf, acc[nt], 0, 0, 0);
        }
    }
    __syncthreads();                             // all sx reads done
    // restage acc into sx as bf16 rows (row-major, stride 136)
#pragma unroll
    for (int nt = 0; nt < 8; ++nt) {
#pragma unroll
        for (int r = 0; r < 4; ++r) {
            sx[(wave * 16 + lg * 4 + r) * 136 + nt * 16 + lr] = f2bf(acc[nt][r]);
        }
    }
    __syncthreads();
    // coalesced flush: 16 threads per row, short8 (8 ushorts, 16B) each
#pragma unroll
    for (int j = 0; j < 4; ++j) {
        int idx = j * 256 + t;                   // 1024 chunks = 64 rows * 16
        int row = idx >> 4, c8 = (idx & 15) * 8;
        int gr = base + row;
        if (gr < M) {
            short8 v = *(const short8*)(&sx[row * 136 + c8]);
            *(short8*)(h + (size_t)gr * D + c8) = v;
        }
    }
}

// ---- pass 1: tile-local LDS sort into 256 super-buckets, contiguous flush ----
// entry = src | (dstLocal << 17); src < 2^17, dstLocal < 512
__global__ __launch_bounds__(BINT) void k_bin(const int* __restrict__ ei, int E,
                                              const int* __restrict__ flagp,
                                              int* __restrict__ g_sbcnt,
                                              unsigned* __restrict__ binned, int C2) {
    __shared__ unsigned stage[TILE];
    __shared__ unsigned char ssb[TILE];
    __shared__ int hcnt[NSB], hoff[NSB], lcur[NSB], gbase[NSB];
    int f64 = *flagp;
    int t = threadIdx.x;
    int base = blockIdx.x * TILE;
    int cnt = E - base; if (cnt > TILE) cnt = TILE;

    if (t < NSB) hcnt[t] = 0;
    __syncthreads();

    unsigned ent[8]; int esb[8];
#pragma unroll
    for (int j = 0; j < 8; ++j) {
        int idx = j * BINT + t;
        esb[j] = -1;
        if (idx < cnt) {
            int e = base + idx;
            int s, d;
            if (f64) {
                s = ((const int2*)ei)[e].x;
                d = ((const int2*)ei)[E + e].x;
            } else {
                s = ei[e];
                d = ei[E + e];
            }
            esb[j] = d >> SBBITS;
            ent[j] = (unsigned)s | ((unsigned)(d & (SBN - 1)) << 17);
            atomicAdd(&hcnt[esb[j]], 1);
        }
    }
    __syncthreads();
    if (t < NSB) hoff[t] = hcnt[t];
    __syncthreads();
#pragma unroll
    for (int off = 1; off < NSB; off <<= 1) {
        int a = (t < NSB && t >= off) ? hoff[t - off] : 0;
        __syncthreads();
        if (t < NSB) hoff[t] += a;
        __syncthreads();
    }
    if (t < NSB) {
        int ex = hoff[t] - hcnt[t];            // exclusive offset
        lcur[t] = ex;
        hoff[t] = ex;
        gbase[t] = (hcnt[t] > 0) ? atomicAdd(&g_sbcnt[t], hcnt[t]) : 0;
    }
    __syncthreads();
#pragma unroll
    for (int j = 0; j < 8; ++j) {
        if (esb[j] >= 0) {
            int p = atomicAdd(&lcur[esb[j]], 1);
            stage[p] = ent[j];
            ssb[p] = (unsigned char)esb[j];
        }
    }
    __syncthreads();
    for (int i = t; i < cnt; i += BINT) {      // lanes write consecutive addrs
        int sb = ssb[i];
        int pos = gbase[sb] + (i - hoff[sb]);
        if (pos < C2) binned[(size_t)sb * C2 + pos] = stage[i];
    }
}

// ---- pass 2: per-super-bucket degree/scan/fill within L2-resident window ----
__global__ __launch_bounds__(1024) void k_fill2(const unsigned* __restrict__ binned, int C2,
                                                const int* __restrict__ g_sbcnt,
                                                int2* __restrict__ ronode,
                                                float* __restrict__ dinv,
                                                int* __restrict__ csrc, int N) {
    __shared__ int deg[SBN];
    __shared__ int scn[SBN];
    __shared__ int cur[SBN];
    int b = blockIdx.x, t = threadIdx.x;
    int cnt = g_sbcnt[b]; if (cnt > C2) cnt = C2;
    const unsigned* ent = binned + (size_t)b * C2;

    if (t < SBN) deg[t] = 0;
    __syncthreads();
    for (int i = t; i < cnt; i += 1024) atomicAdd(&deg[ent[i] >> 17], 1);
    __syncthreads();
    if (t < SBN) scn[t] = deg[t];
    __syncthreads();
    for (int off = 1; off < SBN; off <<= 1) {
        int a = (t < SBN && t >= off) ? scn[t - off] : 0;
        __syncthreads();
        if (t < SBN) scn[t] += a;
        __syncthreads();
    }
    if (t < SBN) {
        int ex = scn[t] - deg[t];
        cur[t] = ex;
        int node = (b << SBBITS) + t;
        if (node < N) {
            ronode[node] = make_int2(b * C2 + ex, deg[t]);
            dinv[node] = deg[t] > 0 ? rsqrtf((float)deg[t]) : 0.0f;
        }
    }
    __syncthreads();
    for (int i = t; i < cnt; i += 1024) {
        unsigned e = ent[i];
        int pos = atomicAdd(&cur[e >> 17], 1);
        csrc[b * C2 + pos] = (int)(e & 0x1FFFF);
    }
}

// ---- aggregation: 1 wave/node, dwordx2 loads (2 edges/instr), bf16 agg out ----
__global__ __launch_bounds__(256) void k_agg(const unsigned long long* __restrict__ h,
                                             const int* __restrict__ csrc,
                                             const int2* __restrict__ ronode,
                                             const float* __restrict__ dinv,
                                             ushort4* __restrict__ aggb, int N) {
    int wave = threadIdx.x >> 6, lane = threadIdx.x & 63;
    int node = blockIdx.x * 4 + wave;
    if (node >= N) return;
    int half = lane >> 5, lq = lane & 31;   // lq: 4-col group; half: edge parity
    int2 ro = ronode[node];
    int beg = ro.x, end = ro.x + ro.y;
    float a0 = 0.f, a1 = 0.f, a2 = 0.f, a3 = 0.f;
    int i = beg;
    for (; i + 16 <= end; i += 16) {
#pragma unroll
        for (int p = 0; p < 8; ++p) {
            int e = i + 2 * p + half;
            int s = csrc[e];
            float w = dinv[s];
            unsigned long long pk = h[(size_t)s * 32 + lq];
            unsigned lo = (unsigned)pk, hi = (unsigned)(pk >> 32);
            a0 += w * bflo(lo); a1 += w * bfhi(lo);
            a2 += w * bflo(hi); a3 += w * bfhi(hi);
        }
    }
    for (; i + 2 <= end; i += 2) {
        int e = i + half;
        int s = csrc[e];
        float w = dinv[s];
        unsigned long long pk = h[(size_t)s * 32 + lq];
        unsigned lo = (unsigned)pk, hi = (unsigned)(pk >> 32);
        a0 += w * bflo(lo); a1 += w * bfhi(lo);
        a2 += w * bflo(hi); a3 += w * bfhi(hi);
    }
    if (i < end) {                           // odd leftover: upper half weight 0
        int s = csrc[i];
        float w = half ? 0.f : dinv[s];
        unsigned long long pk = h[(size_t)s * 32 + lq];
        unsigned lo = (unsigned)pk, hi = (unsigned)(pk >> 32);
        a0 += w * bflo(lo); a1 += w * bfhi(lo);
        a2 += w * bflo(hi); a3 += w * bfhi(hi);
    }
    a0 += __shfl_xor(a0, 32);
    a1 += __shfl_xor(a1, 32);
    a2 += __shfl_xor(a2, 32);
    a3 += __shfl_xor(a3, 32);
    float sd = dinv[node];
    if (half == 0) {
        ushort4 o;
        o.x = f2bf(a0 * sd); o.y = f2bf(a1 * sd);
        o.z = f2bf(a2 * sd); o.w = f2bf(a3 * sd);
        aggb[(size_t)node * 32 + lq] = o;
    }
}

// ---- BN stats from bf16 agg: vectorized ushort4 loads, block partials ----
__global__ __launch_bounds__(256) void k_stats(const ushort4* __restrict__ aggb,
                                               float* __restrict__ part, int N) {
    int t = threadIdx.x;
    int c4 = t & 31, rg = t >> 5;            // col-group (4 cols), row-group (8)
    float s0 = 0.f, s1 = 0.f, s2 = 0.f, s3 = 0.f;
    float q0 = 0.f, q1 = 0.f, q2 = 0.f, q3 = 0.f;
    for (int r = blockIdx.x * 8 + rg; r < N; r += SBLK * 8) {
        ushort4 u = aggb[(size_t)r * 32 + c4];
        float v0 = bf2f(u.x), v1 = bf2f(u.y), v2 = bf2f(u.z), v3 = bf2f(u.w);
        s0 += v0; s1 += v1; s2 += v2; s3 += v3;
        q0 += v0 * v0; q1 += v1 * v1; q2 += v2 * v2; q3 += v3 * v3;
    }
    __shared__ float4 shs[256], shq[256];
    shs[t] = make_float4(s0, s1, s2, s3);
    shq[t] = make_float4(q0, q1, q2, q3);
    __syncthreads();
    if (t < 32) {
        float4 as = shs[t], aq = shq[t];
#pragma unroll
        for (int k = 1; k < 8; ++k) {
            float4 bs = shs[t + 32 * k], bq = shq[t + 32 * k];
            as.x += bs.x; as.y += bs.y; as.z += bs.z; as.w += bs.w;
            aq.x += bq.x; aq.y += bq.y; aq.z += bq.z; aq.w += bq.w;
        }
        *(float4*)&part[blockIdx.x * 256 + t * 4]       = as;
        *(float4*)&part[blockIdx.x * 256 + 128 + t * 4] = aq;
    }
}

__global__ void k_params(const float* __restrict__ part, const float* __restrict__ gamma,
                         const float* __restrict__ beta, float* __restrict__ params, int N) {
    int t = threadIdx.x;   // 256
    float a = 0.f;
    for (int b = 0; b < SBLK; ++b) a += part[b * 256 + t];
    __shared__ float sh[256];
    sh[t] = a;
    __syncthreads();
    if (t < 128) {
        float mean = sh[t] / (float)N;
        float var = sh[128 + t] / (float)N - mean * mean;
        var = var > 0.f ? var : 0.f;
        float sc = gamma[t] * rsqrtf(var + 1e-5f);
        params[t] = sc;
        params[128 + t] = beta[t] - mean * sc;
    }
}

// ---- finalize: out = relu(aggb*scale+shift) + x  (f32 out, bf16 agg in) ----
__global__ __launch_bounds__(256) void k_final(float4* __restrict__ out,
                                               const ushort4* __restrict__ aggb,
                                               const float4* __restrict__ x,
                                               const float* __restrict__ params, int n4) {
    const float4* p4 = (const float4*)params;
    for (int i = blockIdx.x * 256 + threadIdx.x; i < n4; i += gridDim.x * 256) {
        int c = i & 31;
        float4 s = p4[c], b = p4[32 + c];
        ushort4 av = aggb[i];
        float4 xv = x[i];
        float4 r;
        r.x = fmaxf(bf2f(av.x) * s.x + b.x, 0.f) + xv.x;
        r.y = fmaxf(bf2f(av.y) * s.y + b.y, 0.f) + xv.y;
        r.z = fmaxf(bf2f(av.z) * s.z + b.z, 0.f) + xv.z;
        r.w = fmaxf(bf2f(av.w) * s.w + b.w, 0.f) + xv.w;
        out[i] = r;
    }
}

extern "C" void kernel_launch(void* const* d_in, const int* in_sizes, int n_in,
                              void* d_out, int out_size, void* d_ws, size_t ws_size,
                              hipStream_t stream) {
    const float* x     = (const float*)d_in[0];
    const int*   ei    = (const int*)d_in[1];
    const float* W     = (const float*)d_in[2];
    const float* gamma = (const float*)d_in[3];
    const float* beta  = (const float*)d_in[4];

    int N = in_sizes[0] / D;
    int E = in_sizes[1] / 2;
    int NSBu = (N + SBN - 1) >> SBBITS;                    // used super-buckets (<=NSB)
    int avg = (E + NSBu - 1) / NSBu;
    int C2 = ((avg + 4096 + 63) / 64) * 64;                // generous headroom

    char* ws = (char*)d_ws;
    size_t off = 0;
    auto alloc = [&](size_t bytes) { size_t o = off; off = (off + bytes + 255) & ~(size_t)255; return o; };

    size_t binned_bytes = (size_t)NSBu * C2 * 4;
    size_t aggb_bytes   = (size_t)N * D * 2;
    size_t share_bytes  = binned_bytes > aggb_bytes ? binned_bytes : aggb_bytes;

    unsigned short* h    = (unsigned short*)(ws + alloc((size_t)N * D * 2));
    int*      csrc   = (int*)     (ws + alloc((size_t)NSBu * C2 * 4));
    char*     share  =            (ws + alloc(share_bytes));      // binned, then aggb
    unsigned* binned = (unsigned*)share;
    unsigned short* aggb = (unsigned short*)share;                // alias: binned dead after k_fill2
    int*      g_sbcnt= (int*)     (ws + alloc((size_t)NSB * 4));
    float*    dinv   = (float*)   (ws + alloc((size_t)N * 4));
    int2*     ronode = (int2*)    (ws + alloc((size_t)N * 8));
    float*    part   = (float*)   (ws + alloc((size_t)SBLK * 256 * 4));
    float*    params = (float*)   (ws + alloc(256 * 4));
    int*      flagp  = (int*)     (ws + alloc(4));
    unsigned short* Wbf = (unsigned short*)(ws + alloc((size_t)D * D * 2));

    k_prep<<<64, 256, 0, stream>>>((const unsigned*)ei, E, flagp, W, Wbf, g_sbcnt);
    k_gemm<<<(N + 63) / 64, 256, 0, stream>>>(x, Wbf, h, N);
    k_bin<<<(E + TILE - 1) / TILE, BINT, 0, stream>>>(ei, E, flagp, g_sbcnt, binned, C2);
    k_fill2<<<NSBu, 1024, 0, stream>>>(binned, C2, g_sbcnt, ronode, dinv, csrc, N);
    k_agg<<<(N + 3) / 4, 256, 0, stream>>>((const unsigned long long*)h, csrc, ronode, dinv,
                                           (ushort4*)aggb, N);
    k_stats<<<SBLK, 256, 0, stream>>>((const ushort4*)aggb, part, N);
    k_params<<<1, 256, 0, stream>>>(part, gamma, beta, params, N);
    k_final<<<2048, 256, 0, stream>>>((float4*)d_out, (const ushort4*)aggb,
                                      (const float4*)x, params, (N * D) / 4);
}